// Round 20
// baseline (280.355 us; speedup 1.0000x reference)
//
#include <hip/hip_runtime.h>
#include <math.h>

// ---------------------------------------------------------------------------
// CrossPath: dual cross-attention block, MI355X (gfx950).
//   B=4, N=2304, C=256, H=8, D=32, out = 2 x [B,C,96,96] float32
// Inputs float32 (runtime-sniffed). Internal: bf16 MFMA, fp32 accumulation.
// R28: packed-f16 softmax. R26 counters => attn is trans-pipe bound:
// 16 quarter-rate v_exp_f32 per QSET (~256 issue cyc) dominate. Replace
// with full-rate packed-f16 exp2 (magic-constant round + deg-3 poly +
// bit-level 2^n scale; 10 v_pk_* ops per PAIR ~ 160 cyc/QSET). P emerges
// f16-packed -> PV uses mfma_f32_32x32x16_f16 with V4 stored as f16
// (more precise than bf16). K/Q/S^T stay bf16. Everything else = R26.
// ---------------------------------------------------------------------------

typedef __attribute__((ext_vector_type(8))) short short8;   // 8 bf16 = 4 VGPRs
typedef __attribute__((ext_vector_type(8))) _Float16 half8; // 8 f16 = 4 VGPRs
typedef __attribute__((ext_vector_type(4))) float f32x4;
typedef __attribute__((ext_vector_type(16))) float f32x16;
typedef __attribute__((ext_vector_type(2))) unsigned uint32x2;

#define MFMA16(a, b, c) __builtin_amdgcn_mfma_f32_16x16x32_bf16((a), (b), (c), 0, 0, 0)
#define MFMA32(a, b, c) __builtin_amdgcn_mfma_f32_32x32x16_bf16((a), (b), (c), 0, 0, 0)
#define MFMA32H(a, b, c) __builtin_amdgcn_mfma_f32_32x32x16_f16((a), (b), (c), 0, 0, 0)

__device__ __forceinline__ float bf2f(ushort u) {
    union { unsigned u; float f; } x; x.u = ((unsigned)u) << 16; return x.f;
}
__device__ __forceinline__ ushort f2bf(float f) {
    union { float f; unsigned u; } x; x.f = f;
    unsigned u = x.u;
    return (ushort)((u + 0x7fffu + ((u >> 16) & 1u)) >> 16);   // RNE
}
// HW packed RNE conversion: D = {bf16(b)<<16 | bf16(a)}
__device__ __forceinline__ unsigned cvt_pk_bf16(float a, float b) {
    unsigned r;
    asm("v_cvt_pk_bf16_f32 %0, %1, %2" : "=v"(r) : "v"(a), "v"(b));
    return r;
}
// Packed f32->f16 (RTZ): D = {f16(b)<<16 | f16(a)}
__device__ __forceinline__ unsigned pk_cvt_f16(float a, float b) {
    unsigned r;
    asm("v_cvt_pkrtz_f16_f32 %0, %1, %2" : "=v"(r) : "v"(a), "v"(b));
    return r;
}
// Packed f16 helpers (full-rate VOP3P).
__device__ __forceinline__ unsigned pk_addf(unsigned a, unsigned b) {
    unsigned r; asm("v_pk_add_f16 %0, %1, %2" : "=v"(r) : "v"(a), "v"(b)); return r;
}
__device__ __forceinline__ unsigned pk_maxf(unsigned a, unsigned b) {
    unsigned r; asm("v_pk_max_f16 %0, %1, %2" : "=v"(r) : "v"(a), "v"(b)); return r;
}
__device__ __forceinline__ unsigned pk_fmaf(unsigned a, unsigned b, unsigned c) {
    unsigned r; asm("v_pk_fma_f16 %0, %1, %2, %3" : "=v"(r) : "v"(a), "v"(b), "v"(c)); return r;
}
__device__ __forceinline__ unsigned pk_lshl(unsigned sh, unsigned a) {
    unsigned r; asm("v_pk_lshlrev_b16 %0, %1, %2" : "=v"(r) : "v"(sh), "v"(a)); return r;
}
__device__ __forceinline__ unsigned pk_addu(unsigned a, unsigned b) {
    unsigned r; asm("v_pk_add_u16 %0, %1, %2" : "=v"(r) : "v"(a), "v"(b)); return r;
}
__device__ __forceinline__ float cvt_f32_lo(unsigned h) {
    float r; asm("v_cvt_f32_f16 %0, %1" : "=v"(r) : "v"(h)); return r;
}
// Exchange upper 32 lanes of a with lower 32 lanes of b (gfx950 builtin).
__device__ __forceinline__ void plswap(unsigned &a, unsigned &b) {
    uint32x2 r = __builtin_amdgcn_permlane32_swap(a, b, false, false);
    a = r[0]; b = r[1];
}

// ---------------------------------------------------------------------------
// prep: inline dtype sniff (per-wave, from x1) + convert x1/x2 -> bf16 +
// canonicalize the 12 weight/param arrays to bf16 at fixed offsets.
// Grid: 4358 blocks (0..2303 -> x-convert, 2304..4357 -> params).
// ---------------------------------------------------------------------------
__global__ __launch_bounds__(256) void prep_kernel(
    const void* __restrict__ x1, const void* __restrict__ x2,
    ushort* __restrict__ xo1, ushort* __restrict__ xo2,
    const void* s0, const void* s1, const void* s2, const void* s3,
    const void* s4, const void* s5, const void* s6, const void* s7,
    const void* s8, const void* s9, const void* s10, const void* s11,
    ushort* __restrict__ dst)
{
    ushort u = ((const ushort*)x1)[(threadIdx.x & 63) * 2];
    int e = (u >> 7) & 0xFF;
    int outlier = (e < 100 || e > 135) ? 1 : 0;
    unsigned long long mk = __ballot(outlier);
    int flag = (__popcll(mk) >= 16) ? 1 : 0;

    int bid = blockIdx.x;
    if (bid < 2304) {
        int idx = bid * 256 + threadIdx.x;
        int which = idx >= 294912;
        int off = (which ? idx - 294912 : idx) * 8;
        const void* src = which ? x2 : x1;
        ushort* o = which ? xo2 : xo1;
        if (flag) {
            const float* p = (const float*)src + off;
            float4 a = *(const float4*)p;
            float4 c = *(const float4*)(p + 4);
            uint4 u4;
            u4.x = cvt_pk_bf16(a.x, a.y);
            u4.y = cvt_pk_bf16(a.z, a.w);
            u4.z = cvt_pk_bf16(c.x, c.y);
            u4.w = cvt_pk_bf16(c.z, c.w);
            *(uint4*)(o + off) = u4;
        } else {
            *(uint4*)(o + off) = *(const uint4*)((const ushort*)src + off);
        }
    } else {
        int idx = (bid - 2304) * 256 + threadIdx.x;
        if (idx >= 525824) return;
        const void* src; int off;
        if      (idx < 65536)  { src = s0;  off = idx; }
        else if (idx < 196608) { src = s1;  off = idx - 65536; }
        else if (idx < 262144) { src = s2;  off = idx - 196608; }
        else if (idx < 393216) { src = s3;  off = idx - 262144; }
        else if (idx < 458752) { src = s4;  off = idx - 393216; }
        else if (idx < 524288) { src = s5;  off = idx - 458752; }
        else if (idx < 524544) { src = s6;  off = idx - 524288; }
        else if (idx < 524800) { src = s7;  off = idx - 524544; }
        else if (idx < 525056) { src = s8;  off = idx - 524800; }
        else if (idx < 525312) { src = s9;  off = idx - 525056; }
        else if (idx < 525568) { src = s10; off = idx - 525312; }
        else                   { src = s11; off = idx - 525568; }
        ushort v = flag ? f2bf(((const float*)src)[off])
                        : ((const ushort*)src)[off];
        dst[idx] = v;
    }
}

// ---------------------------------------------------------------------------
// GEMM: C[M,N] = A[M,K]*W[N,K]^T, bf16 MFMA 16x16x32, tile 128x128, 4 waves
// in 2x2 (64x64 per wave, acc[4][4], 16 MFMA per k-step per wave).
// mode 1 (merged QKV, N=768): col<256 -> Q row-major SCALED by scale*log2e;
// col<512 -> K4[bh][t32=72][dh=2][tok32=32][d16=16] (bf16); else
// V4[bh][kt16=144][d=32][k16=16] stored as F16. Rows [0,mhalf) -> set 1.
// ---------------------------------------------------------------------------
__global__ __launch_bounds__(256) void gemm_bt(
    const void* __restrict__ Ain, const ushort* __restrict__ W,
    ushort* __restrict__ C, const ushort* __restrict__ bias,
    int M, int N, int K, int relu, const int* __restrict__ dflag, int a_ext,
    int mode, ushort* __restrict__ Kh, ushort* __restrict__ Vt,
    const ushort* __restrict__ W2, const ushort* __restrict__ bias2,
    ushort* __restrict__ Kh2, ushort* __restrict__ Vt2, int mhalf)
{
    __shared__ __align__(16) ushort As[128][40];
    __shared__ __align__(16) ushort Ws[128][40];

    const int m0 = blockIdx.x * 128;
    const int n0 = blockIdx.y * 128;
    const int tid = threadIdx.x;
    const int w = tid >> 6;
    const int wr = w >> 1, wc = w & 1;            // 2x2 wave grid
    const int lane = tid & 63;
    const int lm = lane & 15;
    const int quad = lane >> 4;
    const int a32 = a_ext ? *dflag : 0;

    const int side = (mhalf && m0 >= mhalf) ? 1 : 0;
    const ushort* Wu = side ? W2 : W;
    const ushort* bu = side ? bias2 : bias;
    ushort* Khu = side ? Kh2 : Kh;
    ushort* Vtu = side ? Vt2 : Vt;

    const f32x4 Z4 = {0.f, 0.f, 0.f, 0.f};
    f32x4 acc[4][4];
    for (int i = 0; i < 4; i++)
        for (int j = 0; j < 4; j++) acc[i][j] = Z4;

    const ushort* A16 = (const ushort*)Ain;
    const float*  A32 = (const float*)Ain;
    const int row = tid >> 1, off16 = (tid & 1) * 16;   // 16 elems/thread

    for (int k0 = 0; k0 < K; k0 += 32) {
        __syncthreads();
        if (a32) {
            const float* p0 = A32 + (size_t)(m0 + row) * K + k0 + off16;
            float4 f0 = *(const float4*)p0;
            float4 f1 = *(const float4*)(p0 + 4);
            float4 f2 = *(const float4*)(p0 + 8);
            float4 f3 = *(const float4*)(p0 + 12);
            uint4 t0, t1;
            t0.x = cvt_pk_bf16(f0.x, f0.y);
            t0.y = cvt_pk_bf16(f0.z, f0.w);
            t0.z = cvt_pk_bf16(f1.x, f1.y);
            t0.w = cvt_pk_bf16(f1.z, f1.w);
            t1.x = cvt_pk_bf16(f2.x, f2.y);
            t1.y = cvt_pk_bf16(f2.z, f2.w);
            t1.z = cvt_pk_bf16(f3.x, f3.y);
            t1.w = cvt_pk_bf16(f3.z, f3.w);
            *(uint4*)&As[row][off16]     = t0;
            *(uint4*)&As[row][off16 + 8] = t1;
        } else {
            const ushort* p0 = A16 + (size_t)(m0 + row) * K + k0 + off16;
            *(uint4*)&As[row][off16]     = *(const uint4*)p0;
            *(uint4*)&As[row][off16 + 8] = *(const uint4*)(p0 + 8);
        }
        {
            const ushort* p0 = Wu + (size_t)(n0 + row) * K + k0 + off16;
            *(uint4*)&Ws[row][off16]     = *(const uint4*)p0;
            *(uint4*)&Ws[row][off16 + 8] = *(const uint4*)(p0 + 8);
        }
        __syncthreads();

        short8 af[4], wf[4];
        #pragma unroll
        for (int mt = 0; mt < 4; mt++)
            af[mt] = *(const short8*)&As[wr * 64 + mt * 16 + lm][quad * 8];
        #pragma unroll
        for (int nt = 0; nt < 4; nt++)
            wf[nt] = *(const short8*)&Ws[wc * 64 + nt * 16 + lm][quad * 8];
        #pragma unroll
        for (int mt = 0; mt < 4; mt++)
            #pragma unroll
            for (int nt = 0; nt < 4; nt++)
                acc[mt][nt] = MFMA16(af[mt], wf[nt], acc[mt][nt]);
    }

    if (mode == 1) {
        const float QSC = 0.17677669529663687f * 1.4426950408889634f;
        #pragma unroll
        for (int mt = 0; mt < 4; mt++) {
            const int grow = m0 + wr * 64 + mt * 16 + quad * 4;
            const int grel = grow - (side ? mhalf : 0);
            int bb = grel / 2304;
            int tok = grel - bb * 2304;          // 4-aligned
            #pragma unroll
            for (int nt = 0; nt < 4; nt++) {
                int col = n0 + wc * 64 + nt * 16 + lm;
                if (col < 256) {
                    for (int r = 0; r < 4; r++)
                        C[(size_t)(grow + r) * 256 + col] = f2bf(acc[mt][nt][r] * QSC);
                } else if (col < 512) {
                    int c2 = col - 256, hh = c2 >> 5, d = c2 & 31;
                    size_t kb = ((size_t)(bb * 8 + hh) * 72 + (tok >> 5)) * 1024
                              + (size_t)(d >> 4) * 512 + (size_t)(d & 15);
                    for (int r = 0; r < 4; r++)
                        Khu[kb + (size_t)((tok + r) & 31) * 16] = f2bf(acc[mt][nt][r]);
                } else {
                    int c2 = col - 512, hh = c2 >> 5, d = c2 & 31;
                    size_t vb = ((size_t)(bb * 8 + hh) * 144 + (tok >> 4)) * 512
                              + (size_t)d * 16 + (size_t)(tok & 15);
                    uint2 o;
                    o.x = pk_cvt_f16(acc[mt][nt][0], acc[mt][nt][1]);   // V as f16
                    o.y = pk_cvt_f16(acc[mt][nt][2], acc[mt][nt][3]);
                    *(uint2*)&Vtu[vb] = o;
                }
            }
        }
    } else {
        #pragma unroll
        for (int mt = 0; mt < 4; mt++) {
            const int grow = m0 + wr * 64 + mt * 16 + quad * 4;
            #pragma unroll
            for (int nt = 0; nt < 4; nt++) {
                int col = n0 + wc * 64 + nt * 16 + lm;
                float bv = bu ? bf2f(bu[col]) : 0.f;
                for (int r = 0; r < 4; r++) {
                    float v = acc[mt][nt][r] + bv;
                    if (relu) v = fmaxf(v, 0.f);
                    C[(size_t)(grow + r) * N + col] = f2bf(v);
                }
            }
        }
    }
}

// ---------------------------------------------------------------------------
// Flash cross-attention, S^T form, no-max softmax via PACKED-F16 exp2:
// z = f16(s); T = RNE(z+1536) -> n (magic); f = z-n; p = poly3(f) * 2^n
// (bit-level exponent add). P stays f16-packed -> PV via mfma f16 with
// V4 in f16. Q/K/S^T stay bf16. Split-K: 4 waves x 18 tiles, 2 q-sets.
// Partials combined in-block via LDS (bf16 pairs). 2-tile reg prefetch.
// Grid (stream=64, qb=36), XCD-affine.
// ---------------------------------------------------------------------------
__global__ __launch_bounds__(256) void attn_kernel(
    const ushort* __restrict__ Qa, const ushort* __restrict__ Kha,
    const ushort* __restrict__ Vta, ushort* __restrict__ Oa,
    const ushort* __restrict__ Qb, const ushort* __restrict__ Khb2,
    const ushort* __restrict__ Vtb2, ushort* __restrict__ Ob)
{
    __shared__ unsigned Lo[4][2][64][8];   // 16 KB partial O (bf16 pairs)
    __shared__ float    Ll[4][2][64];      //  2 KB partial l

    const int sid = blockIdx.x;           // 0..63: side*32 + bh (XCD-affine)
    const int qb = blockIdx.y;            // 0..35: 64-q tile
    const int side = sid >> 5;
    const int bh = sid & 31;
    const ushort* Q  = side ? Qb   : Qa;
    const ushort* Kh = side ? Khb2 : Kha;
    const ushort* Vt = side ? Vtb2 : Vta;
    ushort* O        = side ? Ob   : Oa;

    const int b = bh >> 3, h = bh & 7;
    const int tid = threadIdx.x;
    const int w = tid >> 6, lane = tid & 63;
    const int l31 = lane & 31, hl = lane >> 5;

    const int qrow0 = qb * 64 + l31;
    const int qrow1 = qrow0 + 32;
    const ushort* qp0 = Q + ((size_t)b * 2304 + qrow0) * 256 + h * 32 + hl * 8;
    const ushort* qp1 = Q + ((size_t)b * 2304 + qrow1) * 256 + h * 32 + hl * 8;
    const short8 qf0a = *(const short8*)qp0;          // d = hl*8 + j
    const short8 qf1a = *(const short8*)(qp0 + 16);   // d = 16 + hl*8 + j
    const short8 qf0b = *(const short8*)qp1;
    const short8 qf1b = *(const short8*)(qp1 + 16);

    // Packed-f16 exp2 constants.
    const unsigned MN13   = 0xCA80CA80u;   // -13.0 (underflow clamp)
    const unsigned M1536  = 0x66006600u;   // +1536.0 (round magic)
    const unsigned MN1536 = 0xE600E600u;   // -1536.0
    const unsigned MNEG1  = 0xBC00BC00u;   // -1.0
    const unsigned C3     = 0x2B1A2B1Au;   // 0.05548
    const unsigned C2     = 0x33B033B0u;   // 0.24023
    const unsigned C1     = 0x398C398Cu;   // 0.69336
    const unsigned C0     = 0x3C003C00u;   // 1.0
    const unsigned SH10   = 0x000A000Au;   // per-half shift 10

    f32x16 oa, ob;
    #pragma unroll
    for (int i = 0; i < 16; i++) { oa[i] = 0.f; ob[i] = 0.f; }
    const f32x16 Z16 = oa;
    float la = 0.f, lb = 0.f;

    const ushort* kp0 = Kh + (size_t)bh * 73728 + l31 * 16 + hl * 8;
    const ushort* vp0 = Vt + (size_t)bh * 73728 + l31 * 16 + hl * 8;

#define LOADT(kf0v, kf1v, vf0v, vf1v, t) { \
    const ushort* _kp = kp0 + (size_t)(t) * 1024; \
    kf0v = *(const short8*)_kp; \
    kf1v = *(const short8*)(_kp + 512); \
    const ushort* _vp = vp0 + (size_t)(t) * 1024; \
    vf0v = *(const short8*)_vp; \
    vf1v = *(const short8*)(_vp + 512); \
}
#define QSET(kf0v, kf1v, vf0v, vf1v, qf0v, qf1v, oacc, lacc) { \
    f32x16 s = MFMA32(kf0v, qf0v, Z16); \
    s = MFMA32(kf1v, qf1v, s); \
    unsigned P0, P1, P2, P3, P4, P5, P6, P7; \
    _Pragma("unroll") \
    for (int i = 0; i < 8; i++) { \
        unsigned z = pk_cvt_f16(s[2 * i], s[2 * i + 1]); \
        z = pk_maxf(z, MN13); \
        unsigned T = pk_addf(z, M1536); \
        unsigned nf = pk_addf(T, MN1536); \
        unsigned f = pk_fmaf(nf, MNEG1, z); \
        unsigned py = pk_fmaf(f, C3, C2); \
        py = pk_fmaf(f, py, C1); \
        py = pk_fmaf(f, py, C0); \
        unsigned pb = pk_addu(py, pk_lshl(SH10, T)); \
        switch (i) { \
            case 0: P0 = pb; break; case 1: P1 = pb; break; \
            case 2: P2 = pb; break; case 3: P3 = pb; break; \
            case 4: P4 = pb; break; case 5: P5 = pb; break; \
            case 6: P6 = pb; break; default: P7 = pb; break; } \
    } \
    { \
        unsigned t01 = pk_addf(P0, P1), t23 = pk_addf(P2, P3); \
        unsigned t45 = pk_addf(P4, P5), t67 = pk_addf(P6, P7); \
        unsigned tt = pk_addf(pk_addf(t01, t23), pk_addf(t45, t67)); \
        lacc += cvt_f32_lo(tt) + cvt_f32_lo(tt >> 16); \
    } \
    plswap(P0, P2); plswap(P1, P3); plswap(P4, P6); plswap(P5, P7); \
    union { unsigned u[4]; half8 h8; } pA, pB, vA_, vB_; \
    pA.u[0] = P0; pA.u[1] = P1; pA.u[2] = P2; pA.u[3] = P3; \
    pB.u[0] = P4; pB.u[1] = P5; pB.u[2] = P6; pB.u[3] = P7; \
    union { short8 s8; half8 h8; } vc0, vc1; \
    vc0.s8 = vf0v; vc1.s8 = vf1v; \
    oacc = MFMA32H(vc0.h8, pA.h8, oacc); \
    oacc = MFMA32H(vc1.h8, pB.h8, oacc); \
}
#define COMP(kf0v, kf1v, vf0v, vf1v) { \
    QSET(kf0v, kf1v, vf0v, vf1v, qf0a, qf1a, oa, la); \
    QSET(kf0v, kf1v, vf0v, vf1v, qf0b, qf1b, ob, lb); \
}

    short8 kA0, kA1, vA0, vA1;    // set A: even local tiles
    short8 kB0, kB1, vB0, vB1;    // set B: odd local tiles

    const int t0 = w * 18;                        // this wave's first tile

    LOADT(kA0, kA1, vA0, vA1, t0);
    LOADT(kB0, kB1, vB0, vB1, t0 + 1);

    for (int i = 0; i < 9; i++) {                 // local tiles 2i, 2i+1
        COMP(kA0, kA1, vA0, vA1);                 // tile t0+2i
        { int ta = t0 + 2 * i + 2; ta = ta < 72 ? ta : 70;
          LOADT(kA0, kA1, vA0, vA1, ta); }
        COMP(kB0, kB1, vB0, vB1);                 // tile t0+2i+1
        { int tb = t0 + 2 * i + 3; tb = tb < 72 ? tb : 71;
          LOADT(kB0, kB1, vB0, vB1, tb); }
    }
#undef LOADT
#undef QSET
#undef COMP

    // Intra-wave: lane halves hold disjoint key subsets -> reduce l.
    la += __shfl_xor(la, 32, 64);
    lb += __shfl_xor(lb, 32, 64);

    // Publish bf16-packed partials; combine across the 4 key-range waves.
    #pragma unroll
    for (int r = 0; r < 8; r++) {
        Lo[w][0][lane][r] = cvt_pk_bf16(oa[2 * r], oa[2 * r + 1]);
        Lo[w][1][lane][r] = cvt_pk_bf16(ob[2 * r], ob[2 * r + 1]);
    }
    Ll[w][0][lane] = la;
    Ll[w][1][lane] = lb;
    __syncthreads();

    if (w < 2) {                                  // wave w combines qset w
        float os[16];
        #pragma unroll
        for (int r = 0; r < 16; r++) os[r] = 0.f;
        float ls = 0.f;
        #pragma unroll
        for (int u = 0; u < 4; u++) {
            ls += Ll[u][w][lane];
            #pragma unroll
            for (int r = 0; r < 8; r++) {
                unsigned pv = Lo[u][w][lane][r];
                os[2 * r]     += bf2f((ushort)pv);
                os[2 * r + 1] += bf2f((ushort)(pv >> 16));
            }
        }
        float rl = 1.f / ls;
        const int qrow = (w == 0) ? qrow0 : qrow1;
        ushort* op = O + ((size_t)b * 2304 + qrow) * 256 + h * 32 + hl * 4;
        #pragma unroll
        for (int g = 0; g < 4; g++) {
            uint2 o;
            o.x = cvt_pk_bf16(os[4 * g] * rl, os[4 * g + 1] * rl);
            o.y = cvt_pk_bf16(os[4 * g + 2] * rl, os[4 * g + 3] * rl);
            *(uint2*)(op + 8 * g) = o;
        }
    }
}

// ---------------------------------------------------------------------------
// Fused output-projection + bias + ReLU + LayerNorm + transpose:
//   O[18432,256] @ Wp^T -> relu -> LN(C=256) -> Yt[(half*4+b)*256+c][2304]
// Block = 64 tokens x full N=256; 4 waves, wave w owns cols [w*64,w*64+64).
// ---------------------------------------------------------------------------
__global__ __launch_bounds__(256) void projlnt_kernel(
    const ushort* __restrict__ O,
    const ushort* __restrict__ W1c, const ushort* __restrict__ b1v,
    const ushort* __restrict__ g1v, const ushort* __restrict__ t1v,
    const ushort* __restrict__ W2c, const ushort* __restrict__ b2v,
    const ushort* __restrict__ g2v, const ushort* __restrict__ t2v,
    ushort* __restrict__ Yt)
{
    __shared__ __align__(16) ushort As[64][40];    //  5 KB
    __shared__ __align__(16) ushort Ws[256][40];   // 20 KB
    __shared__ float Sred[4][64][2];               //  2 KB

    const int m0 = blockIdx.x * 64;                // 288 blocks
    const int side = (m0 >= 9216) ? 1 : 0;
    const ushort* Wu = side ? W2c : W1c;
    const ushort* bu = side ? b2v : b1v;
    const ushort* gu = side ? g2v : g1v;
    const ushort* tu = side ? t2v : t1v;

    const int tid = threadIdx.x;
    const int w = tid >> 6, lane = tid & 63;
    const int lm = lane & 15, quad = lane >> 4;

    const f32x4 Z4 = {0.f, 0.f, 0.f, 0.f};
    f32x4 acc[4][4];
    for (int i = 0; i < 4; i++)
        for (int j = 0; j < 4; j++) acc[i][j] = Z4;

    const int arow = tid >> 2, aoff = (tid & 3) * 8;

    for (int k0 = 0; k0 < 256; k0 += 32) {
        __syncthreads();
        *(uint4*)&As[arow][aoff] =
            *(const uint4*)(O + (size_t)(m0 + arow) * 256 + k0 + aoff);
        const ushort* wp = Wu + (size_t)tid * 256 + k0;
        *(uint4*)&Ws[tid][0]  = *(const uint4*)(wp);
        *(uint4*)&Ws[tid][8]  = *(const uint4*)(wp + 8);
        *(uint4*)&Ws[tid][16] = *(const uint4*)(wp + 16);
        *(uint4*)&Ws[tid][24] = *(const uint4*)(wp + 24);
        __syncthreads();

        short8 af[4], wf[4];
        #pragma unroll
        for (int mt = 0; mt < 4; mt++)
            af[mt] = *(const short8*)&As[mt * 16 + lm][quad * 8];
        #pragma unroll
        for (int nt = 0; nt < 4; nt++)
            wf[nt] = *(const short8*)&Ws[w * 64 + nt * 16 + lm][quad * 8];
        #pragma unroll
        for (int mt = 0; mt < 4; mt++)
            #pragma unroll
            for (int nt = 0; nt < 4; nt++)
                acc[mt][nt] = MFMA16(af[mt], wf[nt], acc[mt][nt]);
    }

    // bias + relu (f32)
    #pragma unroll
    for (int nt = 0; nt < 4; nt++) {
        float bv = bf2f(bu[w * 64 + nt * 16 + lm]);
        #pragma unroll
        for (int mt = 0; mt < 4; mt++)
            #pragma unroll
            for (int r = 0; r < 4; r++)
                acc[mt][nt][r] = fmaxf(acc[mt][nt][r] + bv, 0.f);
    }

    // per-lane partial sums over this wave's 64 cols
    float s[4][4], q[4][4];
    #pragma unroll
    for (int mt = 0; mt < 4; mt++)
        #pragma unroll
        for (int r = 0; r < 4; r++) {
            float a0 = acc[mt][0][r], a1 = acc[mt][1][r];
            float a2 = acc[mt][2][r], a3 = acc[mt][3][r];
            s[mt][r] = (a0 + a1) + (a2 + a3);
            q[mt][r] = (a0 * a0 + a1 * a1) + (a2 * a2 + a3 * a3);
        }
    #pragma unroll
    for (int off = 1; off < 16; off <<= 1)
        #pragma unroll
        for (int mt = 0; mt < 4; mt++)
            #pragma unroll
            for (int r = 0; r < 4; r++) {
                s[mt][r] += __shfl_xor(s[mt][r], off, 64);
                q[mt][r] += __shfl_xor(q[mt][r], off, 64);
            }
    if (lm == 0) {
        #pragma unroll
        for (int mt = 0; mt < 4; mt++)
            #pragma unroll
            for (int r = 0; r < 4; r++) {
                int rowl = mt * 16 + quad * 4 + r;
                Sred[w][rowl][0] = s[mt][r];
                Sred[w][rowl][1] = q[mt][r];
            }
    }
    __syncthreads();

    // totals + normalize + transposed write
    const int mrel = m0 - side * 9216;
    const int bb = mrel / 2304;
    const int tokb = mrel - bb * 2304;
    #pragma unroll
    for (int mt = 0; mt < 4; mt++) {
        float mu[4], rs[4];
        #pragma unroll
        for (int r = 0; r < 4; r++) {
            int rowl = mt * 16 + quad * 4 + r;
            float S = (Sred[0][rowl][0] + Sred[1][rowl][0])
                    + (Sred[2][rowl][0] + Sred[3][rowl][0]);
            float Qq = (Sred[0][rowl][1] + Sred[1][rowl][1])
                     + (Sred[2][rowl][1] + Sred[3][rowl][1]);
            float m = S * (1.f / 256.f);
            float var = Qq * (1.f / 256.f) - m * m;
            mu[r] = m;
            rs[r] = rsqrtf(var + 1e-5f);
        }
        #pragma unroll
        for (int nt = 0; nt < 4; nt++) {
            int col = w * 64 + nt * 16 + lm;
            float g = bf2f(gu[col]);
            float bt = bf2f(tu[col]);
            float y0 = (acc[mt][nt][0] - mu[0]) * rs[0] * g + bt;
            float y1 = (acc[mt][nt][1] - mu[1]) * rs[1] * g + bt;
            float y2 = (acc[mt][nt][2] - mu[2]) * rs[2] * g + bt;
            float y3 = (acc[mt][nt][3] - mu[3]) * rs[3] * g + bt;
            uint2 o;
            o.x = cvt_pk_bf16(y0, y1);
            o.y = cvt_pk_bf16(y2, y3);
            size_t base = ((size_t)((side * 4 + bb) * 256 + col)) * 2304
                        + tokb + mt * 16 + quad * 4;
            *(uint2*)(Yt + base) = o;
        }
    }
}

// ---------------------------------------------------------------------------
// Bilinear 2x upsample from channel-major Yt[bc][48*48]. Each thread emits
// 4 consecutive outputs (oj = 4t..4t+3) as one float4. 18432 blocks.
// ---------------------------------------------------------------------------
__global__ __launch_bounds__(256) void upsample_kernel(
    const ushort* __restrict__ Yt, float* __restrict__ out)
{
    int idx = blockIdx.x * 256 + threadIdx.x;    // 4,718,592 threads
    int t  = idx % 24;
    int r_ = idx / 24;
    int oi = r_ % 96;
    int bc = r_ / 96;                // 0..2047

    float fi = oi * 0.5f - 0.25f;
    int i0 = (int)floorf(fi);
    float wi = fi - (float)i0;
    int i1 = i0 + 1 < 47 ? i0 + 1 : 47;
    i0 = i0 > 0 ? i0 : 0;
    int j0 = 2 * t;
    int jm = j0 - 1 > 0 ? j0 - 1 : 0;
    int jp = j0 + 2 < 47 ? j0 + 2 : 47;

    const ushort* r0 = Yt + (size_t)bc * 2304 + i0 * 48;
    const ushort* r1 = Yt + (size_t)bc * 2304 + i1 * 48;
    float a0 = bf2f(r0[jm]), b0 = bf2f(r0[j0]), c0 = bf2f(r0[j0 + 1]), d0 = bf2f(r0[jp]);
    float a1 = bf2f(r1[jm]), b1 = bf2f(r1[j0]), c1 = bf2f(r1[j0 + 1]), d1 = bf2f(r1[jp]);
    float u = 1.f - wi;
    float ha = u * a0 + wi * a1;
    float hb = u * b0 + wi * b1;
    float hc = u * c0 + wi * c1;
    float hd = u * d0 + wi * d1;
    float4 o;
    o.x = 0.25f * ha + 0.75f * hb;
    o.y = 0.75f * hb + 0.25f * hc;
    o.z = 0.25f * hb + 0.75f * hc;
    o.w = 0.75f * hc + 0.25f * hd;
    *(float4*)(out + (size_t)bc * 9216 + oi * 96 + t * 4) = o;
}

// ---------------------------------------------------------------------------
extern "C" void kernel_launch(void* const* d_in, const int* in_sizes, int n_in,
                              void* d_out, int out_size, void* d_ws, size_t ws_size,
                              hipStream_t stream)
{
    (void)in_sizes; (void)n_in; (void)out_size; (void)ws_size;

    // ---- Buffer plan (stream-order-safe reuse; ~29.4 MB of ws) ----
    ushort* ws  = (ushort*)d_ws;
    ushort* Q1  = ws;                         // [9216,256]
    ushort* Q2  = Q1  + 2359296;              // contiguous with Q1
    ushort* KV1 = Q2  + 2359296;              // K4_1 + V4_1
    ushort* KV2 = KV1 + 4718592;              // K4_2 + V4_2
    ushort* wc  = KV2 + 4718592;              // canonical params

    ushort* cqkv1w = wc;                      // [768,256] = q1w ++ kv1w
    ushort* cqkv2w = wc + 196608;             // [768,256] = q2w ++ kv2w
    ushort* cp1w  = wc + 393216;
    ushort* cp2w  = wc + 458752;
    ushort* cp1b  = wc + 524288;
    ushort* cp2b  = wc + 524544;
    ushort* cg1   = wc + 524800;
    ushort* cb1   = wc + 525056;
    ushort* cg2   = wc + 525312;
    ushort* cb2   = wc + 525568;

    float*  outf = (float*)d_out;
    ushort* O1  = (ushort*)d_out;             // bf16 staging (dead pre-upsample)
    ushort* O2  = O1 + 2359296;               // contiguous with O1
    ushort* Xb1 = O2 + 2359296;               // bf16 x1 (dead after QKV gemm)
    ushort* Xb2 = Xb1 + 2359296;              // contiguous with Xb1
    ushort* Yt  = Q1;                         // Q1+Q2 dead after attn: 9.4 MB
    (void)Q2; (void)O2; (void)Xb2;

    dim3 blk(256);
    // Prep: sniff + x-convert + param canonicalization, one dispatch.
    prep_kernel<<<dim3(4358), blk, 0, stream>>>(
        d_in[0], d_in[1], Xb1, Xb2,
        d_in[2], d_in[3], d_in[4], d_in[5], d_in[8], d_in[10],
        d_in[9], d_in[11], d_in[12], d_in[13], d_in[14], d_in[15],
        wc);

    // Merged Q+KV projections for BOTH inputs (M=18432, N=768):
    // Q scaled by scale*log2e, K4 bf16 / V4 f16 tiled layouts. 128x128.
    gemm_bt<<<dim3(144, 6), blk, 0, stream>>>(Xb1, cqkv1w, Q1, nullptr,
        18432, 768, 256, 0, nullptr, 0, 1, KV1, KV1 + 2359296,
        cqkv2w, nullptr, KV2, KV2 + 2359296, 9216);

    // Both cross attentions in one dispatch. Grid (stream, qb=36): stream =
    // side*32+bh on blockIdx.x so each stream's 36 blocks share an XCD.
    // 4 waves/block, split-K (18 tiles/wave, 2 q-sets), packed-f16 softmax.
    attn_kernel<<<dim3(64, 36), blk, 0, stream>>>(
        Q1, KV2, KV2 + 2359296, O1,
        Q2, KV1, KV1 + 2359296, O2);

    // Fused proj + bias + ReLU + LayerNorm + transpose (M=18432, 64/block).
    projlnt_kernel<<<dim3(288), blk, 0, stream>>>(
        O1, cp1w, cp1b, cg1, cb1, cp2w, cp2b, cg2, cb2, Yt);

    // Bilinear 2x upsample into d_out (float32, float4/thread).
    upsample_kernel<<<dim3(18432), blk, 0, stream>>>(Yt, outf);
}

// Round 21
// 242.739 us; speedup vs baseline: 1.1550x; 1.1550x over previous
//
#include <hip/hip_runtime.h>
#include <math.h>

// ---------------------------------------------------------------------------
// CrossPath: dual cross-attention block, MI355X (gfx950).
//   B=4, N=2304, C=256, H=8, D=32, out = 2 x [B,C,96,96] float32
// Inputs float32 (runtime-sniffed). Internal: bf16 MFMA, fp32 accumulation.
// R29 = final restore of R26 (best measured: 244.0us / 244.8us; attn 78us).
// Session ledger 475.6 -> 244us. All perturbation directions measured:
// R24 deeper split-K (+8), R25 MFMA l-sum (+9), R28 packed-f16 exp (+39,
// exp runs on the co-issuing trans pipe -- moving it to VALU was a loss),
// R14/R16/R21/R22 null. Pipeline:
//   prep (sniff+convert) -> QKV gemm 128x128 (Q pre-scaled, K4/V4 tiled)
//   -> split-K attn (64q/block, 4 waves x 18 tiles, 2 q-sets/wave,
//      no-LDS K-loop, raw v_exp_f32, bf16-packed LDS combine)
//   -> fused proj+bias+ReLU+LN+transpose -> float4 upsample.
// ---------------------------------------------------------------------------

typedef __attribute__((ext_vector_type(8))) short short8;   // 8 bf16 = 4 VGPRs
typedef __attribute__((ext_vector_type(4))) float f32x4;
typedef __attribute__((ext_vector_type(16))) float f32x16;
typedef __attribute__((ext_vector_type(2))) unsigned uint32x2;

#define MFMA16(a, b, c) __builtin_amdgcn_mfma_f32_16x16x32_bf16((a), (b), (c), 0, 0, 0)
#define MFMA32(a, b, c) __builtin_amdgcn_mfma_f32_32x32x16_bf16((a), (b), (c), 0, 0, 0)

__device__ __forceinline__ float bf2f(ushort u) {
    union { unsigned u; float f; } x; x.u = ((unsigned)u) << 16; return x.f;
}
__device__ __forceinline__ ushort f2bf(float f) {
    union { float f; unsigned u; } x; x.f = f;
    unsigned u = x.u;
    return (ushort)((u + 0x7fffu + ((u >> 16) & 1u)) >> 16);   // RNE
}
// HW packed RNE conversion: D = {bf16(b)<<16 | bf16(a)}
__device__ __forceinline__ unsigned cvt_pk_bf16(float a, float b) {
    unsigned r;
    asm("v_cvt_pk_bf16_f32 %0, %1, %2" : "=v"(r) : "v"(a), "v"(b));
    return r;
}
// Raw HW exp2: single v_exp_f32 (no ocml wrapper). Scores bounded; HW
// underflow->0 is correct here.
__device__ __forceinline__ float fast_ex2(float x) {
    float r;
    asm("v_exp_f32 %0, %1" : "=v"(r) : "v"(x));
    return r;
}
// Exchange upper 32 lanes of a with lower 32 lanes of b (gfx950 builtin).
__device__ __forceinline__ void plswap(unsigned &a, unsigned &b) {
    uint32x2 r = __builtin_amdgcn_permlane32_swap(a, b, false, false);
    a = r[0]; b = r[1];
}

// ---------------------------------------------------------------------------
// prep: inline dtype sniff (per-wave, from x1) + convert x1/x2 -> bf16 +
// canonicalize the 12 weight/param arrays to bf16 at fixed offsets.
// Grid: 4358 blocks (0..2303 -> x-convert, 2304..4357 -> params).
// ---------------------------------------------------------------------------
__global__ __launch_bounds__(256) void prep_kernel(
    const void* __restrict__ x1, const void* __restrict__ x2,
    ushort* __restrict__ xo1, ushort* __restrict__ xo2,
    const void* s0, const void* s1, const void* s2, const void* s3,
    const void* s4, const void* s5, const void* s6, const void* s7,
    const void* s8, const void* s9, const void* s10, const void* s11,
    ushort* __restrict__ dst)
{
    ushort u = ((const ushort*)x1)[(threadIdx.x & 63) * 2];
    int e = (u >> 7) & 0xFF;
    int outlier = (e < 100 || e > 135) ? 1 : 0;
    unsigned long long mk = __ballot(outlier);
    int flag = (__popcll(mk) >= 16) ? 1 : 0;

    int bid = blockIdx.x;
    if (bid < 2304) {
        int idx = bid * 256 + threadIdx.x;
        int which = idx >= 294912;
        int off = (which ? idx - 294912 : idx) * 8;
        const void* src = which ? x2 : x1;
        ushort* o = which ? xo2 : xo1;
        if (flag) {
            const float* p = (const float*)src + off;
            float4 a = *(const float4*)p;
            float4 c = *(const float4*)(p + 4);
            uint4 u4;
            u4.x = cvt_pk_bf16(a.x, a.y);
            u4.y = cvt_pk_bf16(a.z, a.w);
            u4.z = cvt_pk_bf16(c.x, c.y);
            u4.w = cvt_pk_bf16(c.z, c.w);
            *(uint4*)(o + off) = u4;
        } else {
            *(uint4*)(o + off) = *(const uint4*)((const ushort*)src + off);
        }
    } else {
        int idx = (bid - 2304) * 256 + threadIdx.x;
        if (idx >= 525824) return;
        const void* src; int off;
        if      (idx < 65536)  { src = s0;  off = idx; }
        else if (idx < 196608) { src = s1;  off = idx - 65536; }
        else if (idx < 262144) { src = s2;  off = idx - 196608; }
        else if (idx < 393216) { src = s3;  off = idx - 262144; }
        else if (idx < 458752) { src = s4;  off = idx - 393216; }
        else if (idx < 524288) { src = s5;  off = idx - 458752; }
        else if (idx < 524544) { src = s6;  off = idx - 524288; }
        else if (idx < 524800) { src = s7;  off = idx - 524544; }
        else if (idx < 525056) { src = s8;  off = idx - 524800; }
        else if (idx < 525312) { src = s9;  off = idx - 525056; }
        else if (idx < 525568) { src = s10; off = idx - 525312; }
        else                   { src = s11; off = idx - 525568; }
        ushort v = flag ? f2bf(((const float*)src)[off])
                        : ((const ushort*)src)[off];
        dst[idx] = v;
    }
}

// ---------------------------------------------------------------------------
// GEMM: C[M,N] = A[M,K]*W[N,K]^T, bf16 MFMA 16x16x32, tile 128x128, 4 waves
// in 2x2 (64x64 per wave, acc[4][4], 16 MFMA per k-step per wave).
// mode 1 (merged QKV, N=768): col<256 -> Q row-major SCALED by scale*log2e;
// col<512 -> K4[bh][t32=72][dh=2][tok32=32][d16=16]; else
// V4[bh][kt16=144][d=32][k16=16]. Rows [0,mhalf) -> set 1, else set 2.
// ---------------------------------------------------------------------------
__global__ __launch_bounds__(256) void gemm_bt(
    const void* __restrict__ Ain, const ushort* __restrict__ W,
    ushort* __restrict__ C, const ushort* __restrict__ bias,
    int M, int N, int K, int relu, const int* __restrict__ dflag, int a_ext,
    int mode, ushort* __restrict__ Kh, ushort* __restrict__ Vt,
    const ushort* __restrict__ W2, const ushort* __restrict__ bias2,
    ushort* __restrict__ Kh2, ushort* __restrict__ Vt2, int mhalf)
{
    __shared__ __align__(16) ushort As[128][40];
    __shared__ __align__(16) ushort Ws[128][40];

    const int m0 = blockIdx.x * 128;
    const int n0 = blockIdx.y * 128;
    const int tid = threadIdx.x;
    const int w = tid >> 6;
    const int wr = w >> 1, wc = w & 1;            // 2x2 wave grid
    const int lane = tid & 63;
    const int lm = lane & 15;
    const int quad = lane >> 4;
    const int a32 = a_ext ? *dflag : 0;

    const int side = (mhalf && m0 >= mhalf) ? 1 : 0;
    const ushort* Wu = side ? W2 : W;
    const ushort* bu = side ? bias2 : bias;
    ushort* Khu = side ? Kh2 : Kh;
    ushort* Vtu = side ? Vt2 : Vt;

    const f32x4 Z4 = {0.f, 0.f, 0.f, 0.f};
    f32x4 acc[4][4];
    for (int i = 0; i < 4; i++)
        for (int j = 0; j < 4; j++) acc[i][j] = Z4;

    const ushort* A16 = (const ushort*)Ain;
    const float*  A32 = (const float*)Ain;
    const int row = tid >> 1, off16 = (tid & 1) * 16;   // 16 elems/thread

    for (int k0 = 0; k0 < K; k0 += 32) {
        __syncthreads();
        if (a32) {
            const float* p0 = A32 + (size_t)(m0 + row) * K + k0 + off16;
            float4 f0 = *(const float4*)p0;
            float4 f1 = *(const float4*)(p0 + 4);
            float4 f2 = *(const float4*)(p0 + 8);
            float4 f3 = *(const float4*)(p0 + 12);
            uint4 t0, t1;
            t0.x = cvt_pk_bf16(f0.x, f0.y);
            t0.y = cvt_pk_bf16(f0.z, f0.w);
            t0.z = cvt_pk_bf16(f1.x, f1.y);
            t0.w = cvt_pk_bf16(f1.z, f1.w);
            t1.x = cvt_pk_bf16(f2.x, f2.y);
            t1.y = cvt_pk_bf16(f2.z, f2.w);
            t1.z = cvt_pk_bf16(f3.x, f3.y);
            t1.w = cvt_pk_bf16(f3.z, f3.w);
            *(uint4*)&As[row][off16]     = t0;
            *(uint4*)&As[row][off16 + 8] = t1;
        } else {
            const ushort* p0 = A16 + (size_t)(m0 + row) * K + k0 + off16;
            *(uint4*)&As[row][off16]     = *(const uint4*)p0;
            *(uint4*)&As[row][off16 + 8] = *(const uint4*)(p0 + 8);
        }
        {
            const ushort* p0 = Wu + (size_t)(n0 + row) * K + k0 + off16;
            *(uint4*)&Ws[row][off16]     = *(const uint4*)p0;
            *(uint4*)&Ws[row][off16 + 8] = *(const uint4*)(p0 + 8);
        }
        __syncthreads();

        short8 af[4], wf[4];
        #pragma unroll
        for (int mt = 0; mt < 4; mt++)
            af[mt] = *(const short8*)&As[wr * 64 + mt * 16 + lm][quad * 8];
        #pragma unroll
        for (int nt = 0; nt < 4; nt++)
            wf[nt] = *(const short8*)&Ws[wc * 64 + nt * 16 + lm][quad * 8];
        #pragma unroll
        for (int mt = 0; mt < 4; mt++)
            #pragma unroll
            for (int nt = 0; nt < 4; nt++)
                acc[mt][nt] = MFMA16(af[mt], wf[nt], acc[mt][nt]);
    }

    if (mode == 1) {
        const float QSC = 0.17677669529663687f * 1.4426950408889634f;
        #pragma unroll
        for (int mt = 0; mt < 4; mt++) {
            const int grow = m0 + wr * 64 + mt * 16 + quad * 4;
            const int grel = grow - (side ? mhalf : 0);
            int bb = grel / 2304;
            int tok = grel - bb * 2304;          // 4-aligned
            #pragma unroll
            for (int nt = 0; nt < 4; nt++) {
                int col = n0 + wc * 64 + nt * 16 + lm;
                if (col < 256) {
                    for (int r = 0; r < 4; r++)
                        C[(size_t)(grow + r) * 256 + col] = f2bf(acc[mt][nt][r] * QSC);
                } else if (col < 512) {
                    int c2 = col - 256, hh = c2 >> 5, d = c2 & 31;
                    size_t kb = ((size_t)(bb * 8 + hh) * 72 + (tok >> 5)) * 1024
                              + (size_t)(d >> 4) * 512 + (size_t)(d & 15);
                    for (int r = 0; r < 4; r++)
                        Khu[kb + (size_t)((tok + r) & 31) * 16] = f2bf(acc[mt][nt][r]);
                } else {
                    int c2 = col - 512, hh = c2 >> 5, d = c2 & 31;
                    size_t vb = ((size_t)(bb * 8 + hh) * 144 + (tok >> 4)) * 512
                              + (size_t)d * 16 + (size_t)(tok & 15);
                    uint2 o;
                    o.x = cvt_pk_bf16(acc[mt][nt][0], acc[mt][nt][1]);
                    o.y = cvt_pk_bf16(acc[mt][nt][2], acc[mt][nt][3]);
                    *(uint2*)&Vtu[vb] = o;
                }
            }
        }
    } else {
        #pragma unroll
        for (int mt = 0; mt < 4; mt++) {
            const int grow = m0 + wr * 64 + mt * 16 + quad * 4;
            #pragma unroll
            for (int nt = 0; nt < 4; nt++) {
                int col = n0 + wc * 64 + nt * 16 + lm;
                float bv = bu ? bf2f(bu[col]) : 0.f;
                for (int r = 0; r < 4; r++) {
                    float v = acc[mt][nt][r] + bv;
                    if (relu) v = fmaxf(v, 0.f);
                    C[(size_t)(grow + r) * N + col] = f2bf(v);
                }
            }
        }
    }
}

// ---------------------------------------------------------------------------
// Flash cross-attention, S^T form on 32x32x16 MFMA, no-max softmax
// (p = exp2(s) via raw v_exp_f32, Q pre-scaled by scale*log2e in QKV GEMM).
// Split-K: block = 4 waves / 64 q; wave w processes key-tiles
// [w*18, w*18+18) for TWO 32-q sets (amortizes each K/V fragment over
// 8 MFMAs). Partials combined in-block via LDS, packed as bf16 pairs
// (Lo 16KB; total LDS 18.4KB). K4/V4 tiled layouts: tile t -> kf at
// t*1024 (+512 d-half), vf at t*1024 (+512 key-half); each load =
// contiguous 1KB wave-block. 2-tile register prefetch (no barriers in
// K-loop). Grid (stream=64, qb=36), XCD-affine.
// ---------------------------------------------------------------------------
__global__ __launch_bounds__(256) void attn_kernel(
    const ushort* __restrict__ Qa, const ushort* __restrict__ Kha,
    const ushort* __restrict__ Vta, ushort* __restrict__ Oa,
    const ushort* __restrict__ Qb, const ushort* __restrict__ Khb2,
    const ushort* __restrict__ Vtb2, ushort* __restrict__ Ob)
{
    __shared__ unsigned Lo[4][2][64][8];   // 16 KB partial O (bf16 pairs)
    __shared__ float    Ll[4][2][64];      //  2 KB partial l

    const int sid = blockIdx.x;           // 0..63: side*32 + bh (XCD-affine)
    const int qb = blockIdx.y;            // 0..35: 64-q tile
    const int side = sid >> 5;
    const int bh = sid & 31;
    const ushort* Q  = side ? Qb   : Qa;
    const ushort* Kh = side ? Khb2 : Kha;
    const ushort* Vt = side ? Vtb2 : Vta;
    ushort* O        = side ? Ob   : Oa;

    const int b = bh >> 3, h = bh & 7;
    const int tid = threadIdx.x;
    const int w = tid >> 6, lane = tid & 63;
    const int l31 = lane & 31, hl = lane >> 5;

    const int qrow0 = qb * 64 + l31;
    const int qrow1 = qrow0 + 32;
    const ushort* qp0 = Q + ((size_t)b * 2304 + qrow0) * 256 + h * 32 + hl * 8;
    const ushort* qp1 = Q + ((size_t)b * 2304 + qrow1) * 256 + h * 32 + hl * 8;
    const short8 qf0a = *(const short8*)qp0;          // d = hl*8 + j
    const short8 qf1a = *(const short8*)(qp0 + 16);   // d = 16 + hl*8 + j
    const short8 qf0b = *(const short8*)qp1;
    const short8 qf1b = *(const short8*)(qp1 + 16);

    f32x16 oa, ob;
    #pragma unroll
    for (int i = 0; i < 16; i++) { oa[i] = 0.f; ob[i] = 0.f; }
    const f32x16 Z16 = oa;
    float la = 0.f, lb = 0.f;

    const ushort* kp0 = Kh + (size_t)bh * 73728 + l31 * 16 + hl * 8;
    const ushort* vp0 = Vt + (size_t)bh * 73728 + l31 * 16 + hl * 8;

#define LOADT(kf0v, kf1v, vf0v, vf1v, t) { \
    const ushort* _kp = kp0 + (size_t)(t) * 1024; \
    kf0v = *(const short8*)_kp; \
    kf1v = *(const short8*)(_kp + 512); \
    const ushort* _vp = vp0 + (size_t)(t) * 1024; \
    vf0v = *(const short8*)_vp; \
    vf1v = *(const short8*)(_vp + 512); \
}
#define QSET(kf0v, kf1v, vf0v, vf1v, qf0v, qf1v, oacc, lacc) { \
    f32x16 s = MFMA32(kf0v, qf0v, Z16); \
    s = MFMA32(kf1v, qf1v, s); \
    float p[16]; \
    _Pragma("unroll") \
    for (int i = 0; i < 16; i++) p[i] = fast_ex2(s[i]); \
    lacc += (((p[0] + p[1]) + (p[2] + p[3])) + ((p[4] + p[5]) + (p[6] + p[7]))) \
          + (((p[8] + p[9]) + (p[10] + p[11])) + ((p[12] + p[13]) + (p[14] + p[15]))); \
    unsigned c0 = cvt_pk_bf16(p[0],  p[1]); \
    unsigned c1 = cvt_pk_bf16(p[2],  p[3]); \
    unsigned c2 = cvt_pk_bf16(p[4],  p[5]); \
    unsigned c3 = cvt_pk_bf16(p[6],  p[7]); \
    unsigned c4 = cvt_pk_bf16(p[8],  p[9]); \
    unsigned c5 = cvt_pk_bf16(p[10], p[11]); \
    unsigned c6 = cvt_pk_bf16(p[12], p[13]); \
    unsigned c7 = cvt_pk_bf16(p[14], p[15]); \
    plswap(c0, c2); plswap(c1, c3); plswap(c4, c6); plswap(c5, c7); \
    union { unsigned u[4]; short8 s8; } pA, pB; \
    pA.u[0] = c0; pA.u[1] = c1; pA.u[2] = c2; pA.u[3] = c3; \
    pB.u[0] = c4; pB.u[1] = c5; pB.u[2] = c6; pB.u[3] = c7; \
    oacc = MFMA32(vf0v, pA.s8, oacc); \
    oacc = MFMA32(vf1v, pB.s8, oacc); \
}
#define COMP(kf0v, kf1v, vf0v, vf1v) { \
    QSET(kf0v, kf1v, vf0v, vf1v, qf0a, qf1a, oa, la); \
    QSET(kf0v, kf1v, vf0v, vf1v, qf0b, qf1b, ob, lb); \
}

    short8 kA0, kA1, vA0, vA1;    // set A: even local tiles
    short8 kB0, kB1, vB0, vB1;    // set B: odd local tiles

    const int t0 = w * 18;                        // this wave's first tile

    LOADT(kA0, kA1, vA0, vA1, t0);
    LOADT(kB0, kB1, vB0, vB1, t0 + 1);

    for (int i = 0; i < 9; i++) {                 // local tiles 2i, 2i+1
        COMP(kA0, kA1, vA0, vA1);                 // tile t0+2i
        { int ta = t0 + 2 * i + 2; ta = ta < 72 ? ta : 70;
          LOADT(kA0, kA1, vA0, vA1, ta); }
        COMP(kB0, kB1, vB0, vB1);                 // tile t0+2i+1
        { int tb = t0 + 2 * i + 3; tb = tb < 72 ? tb : 71;
          LOADT(kB0, kB1, vB0, vB1, tb); }
    }
#undef LOADT
#undef QSET
#undef COMP

    // Intra-wave: lane halves hold disjoint key subsets -> reduce l.
    la += __shfl_xor(la, 32, 64);
    lb += __shfl_xor(lb, 32, 64);

    // Publish bf16-packed partials; combine across the 4 key-range waves.
    #pragma unroll
    for (int r = 0; r < 8; r++) {
        Lo[w][0][lane][r] = cvt_pk_bf16(oa[2 * r], oa[2 * r + 1]);
        Lo[w][1][lane][r] = cvt_pk_bf16(ob[2 * r], ob[2 * r + 1]);
    }
    Ll[w][0][lane] = la;
    Ll[w][1][lane] = lb;
    __syncthreads();

    if (w < 2) {                                  // wave w combines qset w
        float os[16];
        #pragma unroll
        for (int r = 0; r < 16; r++) os[r] = 0.f;
        float ls = 0.f;
        #pragma unroll
        for (int u = 0; u < 4; u++) {
            ls += Ll[u][w][lane];
            #pragma unroll
            for (int r = 0; r < 8; r++) {
                unsigned pv = Lo[u][w][lane][r];
                os[2 * r]     += bf2f((ushort)pv);
                os[2 * r + 1] += bf2f((ushort)(pv >> 16));
            }
        }
        float rl = 1.f / ls;
        const int qrow = (w == 0) ? qrow0 : qrow1;
        ushort* op = O + ((size_t)b * 2304 + qrow) * 256 + h * 32 + hl * 4;
        #pragma unroll
        for (int g = 0; g < 4; g++) {
            uint2 o;
            o.x = cvt_pk_bf16(os[4 * g] * rl, os[4 * g + 1] * rl);
            o.y = cvt_pk_bf16(os[4 * g + 2] * rl, os[4 * g + 3] * rl);
            *(uint2*)(op + 8 * g) = o;
        }
    }
}

// ---------------------------------------------------------------------------
// Fused output-projection + bias + ReLU + LayerNorm + transpose:
//   O[18432,256] @ Wp^T -> relu -> LN(C=256) -> Yt[(half*4+b)*256+c][2304]
// Block = 64 tokens x full N=256; 4 waves, wave w owns cols [w*64,w*64+64).
// ---------------------------------------------------------------------------
__global__ __launch_bounds__(256) void projlnt_kernel(
    const ushort* __restrict__ O,
    const ushort* __restrict__ W1c, const ushort* __restrict__ b1v,
    const ushort* __restrict__ g1v, const ushort* __restrict__ t1v,
    const ushort* __restrict__ W2c, const ushort* __restrict__ b2v,
    const ushort* __restrict__ g2v, const ushort* __restrict__ t2v,
    ushort* __restrict__ Yt)
{
    __shared__ __align__(16) ushort As[64][40];    //  5 KB
    __shared__ __align__(16) ushort Ws[256][40];   // 20 KB
    __shared__ float Sred[4][64][2];               //  2 KB

    const int m0 = blockIdx.x * 64;                // 288 blocks
    const int side = (m0 >= 9216) ? 1 : 0;
    const ushort* Wu = side ? W2c : W1c;
    const ushort* bu = side ? b2v : b1v;
    const ushort* gu = side ? g2v : g1v;
    const ushort* tu = side ? t2v : t1v;

    const int tid = threadIdx.x;
    const int w = tid >> 6, lane = tid & 63;
    const int lm = lane & 15, quad = lane >> 4;

    const f32x4 Z4 = {0.f, 0.f, 0.f, 0.f};
    f32x4 acc[4][4];
    for (int i = 0; i < 4; i++)
        for (int j = 0; j < 4; j++) acc[i][j] = Z4;

    const int arow = tid >> 2, aoff = (tid & 3) * 8;

    for (int k0 = 0; k0 < 256; k0 += 32) {
        __syncthreads();
        *(uint4*)&As[arow][aoff] =
            *(const uint4*)(O + (size_t)(m0 + arow) * 256 + k0 + aoff);
        const ushort* wp = Wu + (size_t)tid * 256 + k0;
        *(uint4*)&Ws[tid][0]  = *(const uint4*)(wp);
        *(uint4*)&Ws[tid][8]  = *(const uint4*)(wp + 8);
        *(uint4*)&Ws[tid][16] = *(const uint4*)(wp + 16);
        *(uint4*)&Ws[tid][24] = *(const uint4*)(wp + 24);
        __syncthreads();

        short8 af[4], wf[4];
        #pragma unroll
        for (int mt = 0; mt < 4; mt++)
            af[mt] = *(const short8*)&As[mt * 16 + lm][quad * 8];
        #pragma unroll
        for (int nt = 0; nt < 4; nt++)
            wf[nt] = *(const short8*)&Ws[w * 64 + nt * 16 + lm][quad * 8];
        #pragma unroll
        for (int mt = 0; mt < 4; mt++)
            #pragma unroll
            for (int nt = 0; nt < 4; nt++)
                acc[mt][nt] = MFMA16(af[mt], wf[nt], acc[mt][nt]);
    }

    // bias + relu (f32)
    #pragma unroll
    for (int nt = 0; nt < 4; nt++) {
        float bv = bf2f(bu[w * 64 + nt * 16 + lm]);
        #pragma unroll
        for (int mt = 0; mt < 4; mt++)
            #pragma unroll
            for (int r = 0; r < 4; r++)
                acc[mt][nt][r] = fmaxf(acc[mt][nt][r] + bv, 0.f);
    }

    // per-lane partial sums over this wave's 64 cols
    float s[4][4], q[4][4];
    #pragma unroll
    for (int mt = 0; mt < 4; mt++)
        #pragma unroll
        for (int r = 0; r < 4; r++) {
            float a0 = acc[mt][0][r], a1 = acc[mt][1][r];
            float a2 = acc[mt][2][r], a3 = acc[mt][3][r];
            s[mt][r] = (a0 + a1) + (a2 + a3);
            q[mt][r] = (a0 * a0 + a1 * a1) + (a2 * a2 + a3 * a3);
        }
    #pragma unroll
    for (int off = 1; off < 16; off <<= 1)
        #pragma unroll
        for (int mt = 0; mt < 4; mt++)
            #pragma unroll
            for (int r = 0; r < 4; r++) {
                s[mt][r] += __shfl_xor(s[mt][r], off, 64);
                q[mt][r] += __shfl_xor(q[mt][r], off, 64);
            }
    if (lm == 0) {
        #pragma unroll
        for (int mt = 0; mt < 4; mt++)
            #pragma unroll
            for (int r = 0; r < 4; r++) {
                int rowl = mt * 16 + quad * 4 + r;
                Sred[w][rowl][0] = s[mt][r];
                Sred[w][rowl][1] = q[mt][r];
            }
    }
    __syncthreads();

    // totals + normalize + transposed write
    const int mrel = m0 - side * 9216;
    const int bb = mrel / 2304;
    const int tokb = mrel - bb * 2304;
    #pragma unroll
    for (int mt = 0; mt < 4; mt++) {
        float mu[4], rs[4];
        #pragma unroll
        for (int r = 0; r < 4; r++) {
            int rowl = mt * 16 + quad * 4 + r;
            float S = (Sred[0][rowl][0] + Sred[1][rowl][0])
                    + (Sred[2][rowl][0] + Sred[3][rowl][0]);
            float Qq = (Sred[0][rowl][1] + Sred[1][rowl][1])
                     + (Sred[2][rowl][1] + Sred[3][rowl][1]);
            float m = S * (1.f / 256.f);
            float var = Qq * (1.f / 256.f) - m * m;
            mu[r] = m;
            rs[r] = rsqrtf(var + 1e-5f);
        }
        #pragma unroll
        for (int nt = 0; nt < 4; nt++) {
            int col = w * 64 + nt * 16 + lm;
            float g = bf2f(gu[col]);
            float bt = bf2f(tu[col]);
            float y0 = (acc[mt][nt][0] - mu[0]) * rs[0] * g + bt;
            float y1 = (acc[mt][nt][1] - mu[1]) * rs[1] * g + bt;
            float y2 = (acc[mt][nt][2] - mu[2]) * rs[2] * g + bt;
            float y3 = (acc[mt][nt][3] - mu[3]) * rs[3] * g + bt;
            uint2 o;
            o.x = cvt_pk_bf16(y0, y1);
            o.y = cvt_pk_bf16(y2, y3);
            size_t base = ((size_t)((side * 4 + bb) * 256 + col)) * 2304
                        + tokb + mt * 16 + quad * 4;
            *(uint2*)(Yt + base) = o;
        }
    }
}

// ---------------------------------------------------------------------------
// Bilinear 2x upsample from channel-major Yt[bc][48*48]. Each thread emits
// 4 consecutive outputs (oj = 4t..4t+3) as one float4. 18432 blocks.
// ---------------------------------------------------------------------------
__global__ __launch_bounds__(256) void upsample_kernel(
    const ushort* __restrict__ Yt, float* __restrict__ out)
{
    int idx = blockIdx.x * 256 + threadIdx.x;    // 4,718,592 threads
    int t  = idx % 24;
    int r_ = idx / 24;
    int oi = r_ % 96;
    int bc = r_ / 96;                // 0..2047

    float fi = oi * 0.5f - 0.25f;
    int i0 = (int)floorf(fi);
    float wi = fi - (float)i0;
    int i1 = i0 + 1 < 47 ? i0 + 1 : 47;
    i0 = i0 > 0 ? i0 : 0;
    int j0 = 2 * t;
    int jm = j0 - 1 > 0 ? j0 - 1 : 0;
    int jp = j0 + 2 < 47 ? j0 + 2 : 47;

    const ushort* r0 = Yt + (size_t)bc * 2304 + i0 * 48;
    const ushort* r1 = Yt + (size_t)bc * 2304 + i1 * 48;
    float a0 = bf2f(r0[jm]), b0 = bf2f(r0[j0]), c0 = bf2f(r0[j0 + 1]), d0 = bf2f(r0[jp]);
    float a1 = bf2f(r1[jm]), b1 = bf2f(r1[j0]), c1 = bf2f(r1[j0 + 1]), d1 = bf2f(r1[jp]);
    float u = 1.f - wi;
    float ha = u * a0 + wi * a1;
    float hb = u * b0 + wi * b1;
    float hc = u * c0 + wi * c1;
    float hd = u * d0 + wi * d1;
    float4 o;
    o.x = 0.25f * ha + 0.75f * hb;
    o.y = 0.75f * hb + 0.25f * hc;
    o.z = 0.25f * hb + 0.75f * hc;
    o.w = 0.75f * hc + 0.25f * hd;
    *(float4*)(out + (size_t)bc * 9216 + oi * 96 + t * 4) = o;
}

// ---------------------------------------------------------------------------
extern "C" void kernel_launch(void* const* d_in, const int* in_sizes, int n_in,
                              void* d_out, int out_size, void* d_ws, size_t ws_size,
                              hipStream_t stream)
{
    (void)in_sizes; (void)n_in; (void)out_size; (void)ws_size;

    // ---- Buffer plan (stream-order-safe reuse; ~29.4 MB of ws) ----
    ushort* ws  = (ushort*)d_ws;
    ushort* Q1  = ws;                         // [9216,256]
    ushort* Q2  = Q1  + 2359296;              // contiguous with Q1
    ushort* KV1 = Q2  + 2359296;              // K4_1 + V4_1
    ushort* KV2 = KV1 + 4718592;              // K4_2 + V4_2
    ushort* wc  = KV2 + 4718592;              // canonical params

    ushort* cqkv1w = wc;                      // [768,256] = q1w ++ kv1w
    ushort* cqkv2w = wc + 196608;             // [768,256] = q2w ++ kv2w
    ushort* cp1w  = wc + 393216;
    ushort* cp2w  = wc + 458752;
    ushort* cp1b  = wc + 524288;
    ushort* cp2b  = wc + 524544;
    ushort* cg1   = wc + 524800;
    ushort* cb1   = wc + 525056;
    ushort* cg2   = wc + 525312;
    ushort* cb2   = wc + 525568;

    float*  outf = (float*)d_out;
    ushort* O1  = (ushort*)d_out;             // bf16 staging (dead pre-upsample)
    ushort* O2  = O1 + 2359296;               // contiguous with O1
    ushort* Xb1 = O2 + 2359296;               // bf16 x1 (dead after QKV gemm)
    ushort* Xb2 = Xb1 + 2359296;              // contiguous with Xb1
    ushort* Yt  = Q1;                         // Q1+Q2 dead after attn: 9.4 MB
    (void)Q2; (void)O2; (void)Xb2;

    dim3 blk(256);
    // Prep: sniff + x-convert + param canonicalization, one dispatch.
    prep_kernel<<<dim3(4358), blk, 0, stream>>>(
        d_in[0], d_in[1], Xb1, Xb2,
        d_in[2], d_in[3], d_in[4], d_in[5], d_in[8], d_in[10],
        d_in[9], d_in[11], d_in[12], d_in[13], d_in[14], d_in[15],
        wc);

    // Merged Q+KV projections for BOTH inputs (M=18432, N=768):
    // Q scaled by scale*log2e, K4/V4 tiled layouts. 128x128 tiles.
    gemm_bt<<<dim3(144, 6), blk, 0, stream>>>(Xb1, cqkv1w, Q1, nullptr,
        18432, 768, 256, 0, nullptr, 0, 1, KV1, KV1 + 2359296,
        cqkv2w, nullptr, KV2, KV2 + 2359296, 9216);

    // Both cross attentions in one dispatch. Grid (stream, qb=36): stream =
    // side*32+bh on blockIdx.x so each stream's 36 blocks share an XCD.
    // 4 waves/block, split-K (18 tiles/wave, 2 q-sets), bf16 LDS combine.
    attn_kernel<<<dim3(64, 36), blk, 0, stream>>>(
        Q1, KV2, KV2 + 2359296, O1,
        Q2, KV1, KV1 + 2359296, O2);

    // Fused proj + bias + ReLU + LayerNorm + transpose (M=18432, 64/block).
    projlnt_kernel<<<dim3(288), blk, 0, stream>>>(
        O1, cp1w, cp1b, cg1, cb1, cp2w, cp2b, cg2, cb2, Yt);

    // Bilinear 2x upsample into d_out (float32, float4/thread).
    upsample_kernel<<<dim3(18432), blk, 0, stream>>>(Yt, outf);
}